// Round 7
// baseline (470.406 us; speedup 1.0000x reference)
//
#include <hip/hip_runtime.h>

// Problem constants (fixed shapes from setup_inputs)
#define HH 540
#define WW 960
#define NC 3
#define ND 60          // disparities 1..60
#define NP (HH * WW)   // 518400 pixels per plane
#define XT 256         // cols per x-tile in k_vq
#define YS 90          // rows per y-strip in k_vq (540 = 6*90; 90 = 9*10)
#define RY 4           // rows per block in k_cost_h (540 = 135*4)

// ---------------------------------------------------------------------------
// Kernel 1: channel-summed horizontal 9-window sums (zero padding on x)
// ---------------------------------------------------------------------------
__global__ __launch_bounds__(256) void k_stats_h(
    const float* __restrict__ L, const float* __restrict__ R,
    float* __restrict__ hsL, float* __restrict__ hsLL,
    float* __restrict__ hsR, float* __restrict__ hsRR) {
    int x = blockIdx.x * blockDim.x + threadIdx.x;
    int y = blockIdx.y;
    if (x >= WW) return;
    float a = 0.f, a2 = 0.f, b = 0.f, b2 = 0.f;
#pragma unroll
    for (int dx = -4; dx <= 4; ++dx) {
        int xx = x + dx;
        if (xx < 0 || xx >= WW) continue;
#pragma unroll
        for (int c = 0; c < NC; ++c) {
            float l = L[(c * HH + y) * WW + xx];
            float r = R[(c * HH + y) * WW + xx];
            a += l; a2 = fmaf(l, l, a2);
            b += r; b2 = fmaf(r, r, b2);
        }
    }
    int o = y * WW + x;
    hsL[o] = a; hsLL[o] = a2; hsR[o] = b; hsRR[o] = b2;
}

// ---------------------------------------------------------------------------
// Kernel 2: vertical 9-window sums + finalize stats
// ---------------------------------------------------------------------------
__global__ __launch_bounds__(256) void k_stats_v(
    const float* __restrict__ hsL, const float* __restrict__ hsLL,
    const float* __restrict__ hsR, const float* __restrict__ hsRR,
    float* __restrict__ LSum, float* __restrict__ sqLa,
    float* __restrict__ RSn, float* __restrict__ sqRa) {
    int x = blockIdx.x * blockDim.x + threadIdx.x;
    int y = blockIdx.y;
    if (x >= WW) return;
    float a = 0.f, a2 = 0.f, b = 0.f, b2 = 0.f;
#pragma unroll
    for (int dy = -4; dy <= 4; ++dy) {
        int yy = y + dy;
        if (yy < 0 || yy >= HH) continue;
        int o = yy * WW + x;
        a += hsL[o]; a2 += hsLL[o]; b += hsR[o]; b2 += hsRR[o];
    }
    const float inv_n = 1.0f / 243.0f;
    int o = y * WW + x;
    LSum[o] = a;
    sqLa[o] = sqrtf(fmaf(-a * inv_n, a, a2) + 1e-5f);
    RSn[o]  = b * inv_n;
    sqRa[o] = sqrtf(fmaf(-b * inv_n, b, b2) + 1e-5f);
}

// ---------------------------------------------------------------------------
// Kernel 3: vertical 9-sum of the per-disparity product image.
//   p_d(y,x) = sum_c L[c,y,x] * R[c,y,x-d]   (0 for x<d or y outside)
//   vq(d,y,x) = sum_{dy=-4..4} p_d(y+dy, x)
// One thread per (d, x) column; walks YS rows with a 9-deep register ring
// (statically indexed via unroll-9). No LDS, no barriers — pure streaming.
// ---------------------------------------------------------------------------
__global__ __launch_bounds__(256) void k_vq(
    const float* __restrict__ L, const float* __restrict__ R,
    float* __restrict__ vq) {
    const int t  = threadIdx.x;
    const int x  = blockIdx.x * XT + t;
    const int y0 = blockIdx.y * YS;      // multiple of 9
    const int d  = blockIdx.z + 1;
    if (x >= WW) return;
    float* const vqd = vq + (size_t)blockIdx.z * NP;

    if (x < d) {                          // shifted R is zero-filled here
        for (int y = y0; y < y0 + YS; ++y) vqd[y * WW + x] = 0.f;
        return;
    }
    const float* const Lx = L + x;
    const float* const Rx = R + (x - d);
    auto pval = [&](int row) -> float {
        if ((unsigned)row >= (unsigned)HH) return 0.f;
        const int o = row * WW;
        float q = Lx[o] * Rx[o];
        q = fmaf(Lx[o + NP],     Rx[o + NP],     q);
        q = fmaf(Lx[o + 2 * NP], Rx[o + 2 * NP], q);
        return q;
    };

    // invariant: ring[r % 9] == p(r); y0 % 9 == 0 so slots are compile-time
    float ring[9];
    float S = 0.f;
#pragma unroll
    for (int j = 0; j < 9; ++j) {         // rows y0-4 .. y0+4
        float p = pval(y0 - 4 + j);
        ring[(j + 5) % 9] = p;            // (y0-4+j) mod 9
        S += p;
    }
    for (int yb = 0; yb < YS; yb += 9) {
#pragma unroll
        for (int j = 0; j < 9; ++j) {
            const int y = y0 + yb + j;
            vqd[y * WW + x] = S;
            const float pnew = pval(y + 5);
            const int slot = (j + 5) % 9; // (y+5) mod 9; holds p(y-4)
            S += pnew - ring[slot];
            ring[slot] = pnew;
        }
    }
}

// ---------------------------------------------------------------------------
// Kernel 4: horizontal 9-sum of vq + NCC finalize + both output planes.
// Thread t owns 4 consecutive cols X=4t of row(s); window X-4..X+7 is three
// aligned float4 loads (left/right zero-pad falls on whole-vector t==0 /
// t==239). costR(d,y,x-d) == costL(d,y,x) identity (HW-validated r1).
// No LDS, no barriers.
// ---------------------------------------------------------------------------
__global__ __launch_bounds__(256) void k_cost_h(
    const float* __restrict__ vq,
    const float* __restrict__ LSum, const float* __restrict__ sqLa,
    const float* __restrict__ RSn, const float* __restrict__ sqRa,
    float* __restrict__ out) {
    const int t = threadIdx.x;
    const int X = 4 * t;
    if (X >= WW) return;
    const int d  = blockIdx.y + 1;
    const int y0 = blockIdx.x * RY;
    const float* const vqd = vq + (size_t)blockIdx.y * NP;
    float* const outLp = out + (size_t)blockIdx.y * NP;
    float* const outRp = outLp + (size_t)ND * NP;
    const float4 z4 = make_float4(0.f, 0.f, 0.f, 0.f);

    for (int y = y0; y < y0 + RY; ++y) {
        const int o = y * WW + X;
        const float4 w0 = (t > 0)   ? *(const float4*)&vqd[o - 4] : z4;
        const float4 w1 = *(const float4*)&vqd[o];
        const float4 w2 = (X + 4 < WW) ? *(const float4*)&vqd[o + 4] : z4;
        const float s0 = ((w0.x + w0.y) + (w0.z + w0.w))
                       + ((w1.x + w1.y) + (w1.z + w1.w)) + w2.x;
        const float s1 = s0 + w2.y - w0.x;
        const float s2 = s1 + w2.z - w0.y;
        const float s3 = s2 + w2.w - w0.z;
        const float s[4] = {s0, s1, s2, s3};

        const float4 ls = *(const float4*)&LSum[o];
        const float4 sl = *(const float4*)&sqLa[o];
        const float lsa[4] = {ls.x, ls.y, ls.z, ls.w};
        const float sla[4] = {sl.x, sl.y, sl.z, sl.w};

        if (X >= d && X + 3 < WW - d) {
            // interior fast path: all 4 outputs valid, no zero regions
            const int od = o - d;
            float cl[4];
#pragma unroll
            for (int j = 0; j < 4; ++j) {
                const float num = fmaf(-lsa[j], RSn[od + j], s[j]) + 1e-6f;
                const float den = fmaf(sla[j], sqRa[od + j], 1e-6f);
                cl[j] = num * __builtin_amdgcn_rcpf(den);
                outRp[od + j] = cl[j];
            }
            *(float4*)&outLp[o] = make_float4(cl[0], cl[1], cl[2], cl[3]);
        } else {
#pragma unroll
            for (int j = 0; j < 4; ++j) {
                const int x = X + j;
                float cl = 0.f;
                if (x >= d) {
                    const int od = o + j - d;
                    const float num = fmaf(-lsa[j], RSn[od], s[j]) + 1e-6f;
                    const float den = fmaf(sla[j], sqRa[od], 1e-6f);
                    cl = num * __builtin_amdgcn_rcpf(den);
                    outRp[od] = cl;
                }
                outLp[o + j] = cl;
                if (x >= WW - d) outRp[o + j] = 0.f;
            }
        }
    }
}

// ---------------------------------------------------------------------------
extern "C" void kernel_launch(void* const* d_in, const int* in_sizes, int n_in,
                              void* d_out, int out_size, void* d_ws, size_t ws_size,
                              hipStream_t stream) {
    const float* L = (const float*)d_in[0];
    const float* R = (const float*)d_in[1];
    float* out = (float*)d_out;
    float* ws = (float*)d_ws;

    float* hsL  = ws + 0 * (size_t)NP;
    float* hsLL = ws + 1 * (size_t)NP;
    float* hsR  = ws + 2 * (size_t)NP;
    float* hsRR = ws + 3 * (size_t)NP;
    float* LSum = ws + 4 * (size_t)NP;
    float* sqLa = ws + 5 * (size_t)NP;
    float* RSn  = ws + 6 * (size_t)NP;
    float* sqRa = ws + 7 * (size_t)NP;
    float* vq   = ws + 8 * (size_t)NP;   // 60 * NP floats = 124.4 MB

    dim3 blk(256);
    dim3 g1((WW + 255) / 256, HH);
    k_stats_h<<<g1, blk, 0, stream>>>(L, R, hsL, hsLL, hsR, hsRR);
    k_stats_v<<<g1, blk, 0, stream>>>(hsL, hsLL, hsR, hsRR, LSum, sqLa, RSn, sqRa);

    dim3 g2((WW + XT - 1) / XT, HH / YS, ND);     // (4, 6, 60)
    k_vq<<<g2, blk, 0, stream>>>(L, R, vq);

    dim3 g3(HH / RY, ND);                          // (135, 60)
    k_cost_h<<<g3, blk, 0, stream>>>(vq, LSum, sqLa, RSn, sqRa, out);
}

// Round 8
// 447.596 us; speedup vs baseline: 1.0510x; 1.0510x over previous
//
#include <hip/hip_runtime.h>

// Problem constants (fixed shapes from setup_inputs)
#define HH 540
#define WW 960
#define NC 3
#define ND 60          // disparities 1..60
#define NP (HH * WW)   // 518400 pixels per plane
#define YS 36          // rows per y-strip in k_vq (540 = 15*36; 36 % 9 == 0)
#define RY 4           // rows per block in k_cost_h (540 = 135*4)

typedef float f4  __attribute__((ext_vector_type(4)));              // 16B-aligned
typedef float f4u __attribute__((ext_vector_type(4), aligned(4)));  // 4B-aligned

// ---------------------------------------------------------------------------
// Kernel 1: channel-summed horizontal 9-window sums (zero padding on x)
// ---------------------------------------------------------------------------
__global__ __launch_bounds__(256) void k_stats_h(
    const float* __restrict__ L, const float* __restrict__ R,
    float* __restrict__ hsL, float* __restrict__ hsLL,
    float* __restrict__ hsR, float* __restrict__ hsRR) {
    int x = blockIdx.x * blockDim.x + threadIdx.x;
    int y = blockIdx.y;
    if (x >= WW) return;
    float a = 0.f, a2 = 0.f, b = 0.f, b2 = 0.f;
#pragma unroll
    for (int dx = -4; dx <= 4; ++dx) {
        int xx = x + dx;
        if (xx < 0 || xx >= WW) continue;
#pragma unroll
        for (int c = 0; c < NC; ++c) {
            float l = L[(c * HH + y) * WW + xx];
            float r = R[(c * HH + y) * WW + xx];
            a += l; a2 = fmaf(l, l, a2);
            b += r; b2 = fmaf(r, r, b2);
        }
    }
    int o = y * WW + x;
    hsL[o] = a; hsLL[o] = a2; hsR[o] = b; hsRR[o] = b2;
}

// ---------------------------------------------------------------------------
// Kernel 2: vertical 9-window sums + finalize stats
// ---------------------------------------------------------------------------
__global__ __launch_bounds__(256) void k_stats_v(
    const float* __restrict__ hsL, const float* __restrict__ hsLL,
    const float* __restrict__ hsR, const float* __restrict__ hsRR,
    float* __restrict__ LSum, float* __restrict__ sqLa,
    float* __restrict__ RSn, float* __restrict__ sqRa) {
    int x = blockIdx.x * blockDim.x + threadIdx.x;
    int y = blockIdx.y;
    if (x >= WW) return;
    float a = 0.f, a2 = 0.f, b = 0.f, b2 = 0.f;
#pragma unroll
    for (int dy = -4; dy <= 4; ++dy) {
        int yy = y + dy;
        if (yy < 0 || yy >= HH) continue;
        int o = yy * WW + x;
        a += hsL[o]; a2 += hsLL[o]; b += hsR[o]; b2 += hsRR[o];
    }
    const float inv_n = 1.0f / 243.0f;
    int o = y * WW + x;
    LSum[o] = a;
    sqLa[o] = sqrtf(fmaf(-a * inv_n, a, a2) + 1e-5f);
    RSn[o]  = b * inv_n;
    sqRa[o] = sqrtf(fmaf(-b * inv_n, b, b2) + 1e-5f);
}

// ---------------------------------------------------------------------------
// Kernel 3: vertical 9-sum of per-disparity product image, 4 cols/thread.
//   vq(d,y,x) = sum_{dy=-4..4} sum_c L[c,y+dy,x] * R[c,y+dy,x-d]
// Grid (d fastest = 60, strips = 15). Thread t owns cols 4t..4t+3; walks YS
// rows with a float4 9-ring (statically indexed). No LDS, no barriers.
// d-fastest grid: 60 consecutive blocks re-read the same L/R rows -> L2 hits.
// ---------------------------------------------------------------------------
__global__ __launch_bounds__(256) void k_vq(
    const float* __restrict__ L, const float* __restrict__ R,
    float* __restrict__ vq) {
    const int t  = threadIdx.x;
    const int X  = 4 * t;
    if (X >= WW) return;
    const int d  = blockIdx.x + 1;
    const int y0 = blockIdx.y * YS;      // multiple of 9
    float* const vqd = vq + (size_t)blockIdx.x * NP;

    if (X + 3 < d) {                     // fully in zero region
        f4 z = (f4)0.f;
        for (int y = y0; y < y0 + YS; ++y) *(f4*)&vqd[y * WW + X] = z;
        return;
    }

    const bool safe = (X >= d);          // all 4 cols valid -> vector loads

    auto pval4 = [&](int row) -> f4 {
        f4 q = (f4)0.f;
        if ((unsigned)row >= (unsigned)HH) return q;
        const int o = row * WW;
        if (safe) {
            const int ox = o + X, or_ = o + X - d;
#pragma unroll
            for (int c = 0; c < NC; ++c) {
                f4  lv = *(const f4*)(L + c * NP + ox);
                f4u rv = *(const f4u*)(R + c * NP + or_);
                q += lv * (f4)rv;
            }
        } else {                          // straddle: per-component guard
#pragma unroll
            for (int j = 0; j < 4; ++j) {
                const int x = X + j;
                if (x >= d) {
                    float s = L[o + x] * R[o + x - d];
                    s = fmaf(L[NP + o + x],     R[NP + o + x - d],     s);
                    s = fmaf(L[2 * NP + o + x], R[2 * NP + o + x - d], s);
                    q[j] = s;
                }
            }
        }
        return q;
    };

    // invariant: ring[r % 9] == p(r); y0 % 9 == 0 so slots are compile-time
    f4 ring[9];
    f4 S = (f4)0.f;
#pragma unroll
    for (int j = 0; j < 9; ++j) {        // rows y0-4 .. y0+4
        f4 p = pval4(y0 - 4 + j);
        ring[(j + 5) % 9] = p;           // (y0-4+j) mod 9
        S += p;
    }
    for (int yb = 0; yb < YS; yb += 9) {
#pragma unroll
        for (int j = 0; j < 9; ++j) {
            const int y = y0 + yb + j;
            *(f4*)&vqd[y * WW + X] = S;
            const f4 pnew = pval4(y + 5);
            const int slot = (j + 5) % 9; // (y+5) mod 9; holds p(y-4)
            S += pnew - ring[slot];
            ring[slot] = pnew;
        }
    }
}

// ---------------------------------------------------------------------------
// Kernel 4: horizontal 9-sum of vq + NCC finalize + both output planes.
// Grid (d fastest = 60, ygroups = 135): consecutive blocks share the same
// 4-row stats window -> L2 reuse across d. Thread t owns 4 cols X=4t.
// All loads/stores vectorized (unaligned f4u where shifted by d).
// costR(d,y,x-d) == costL(d,y,x) identity (HW-validated r1).
// ---------------------------------------------------------------------------
__global__ __launch_bounds__(256) void k_cost_h(
    const float* __restrict__ vq,
    const float* __restrict__ LSum, const float* __restrict__ sqLa,
    const float* __restrict__ RSn, const float* __restrict__ sqRa,
    float* __restrict__ out) {
    const int t = threadIdx.x;
    const int X = 4 * t;
    if (X >= WW) return;
    const int d  = blockIdx.x + 1;
    const int y0 = blockIdx.y * RY;
    const float* const vqd = vq + (size_t)blockIdx.x * NP;
    float* const outLp = out + (size_t)blockIdx.x * NP;
    float* const outRp = outLp + (size_t)ND * NP;
    const f4 z4 = (f4)0.f;

    for (int y = y0; y < y0 + RY; ++y) {
        const int o = y * WW + X;
        const f4 w0 = (t > 0)        ? *(const f4*)&vqd[o - 4] : z4;
        const f4 w1 = *(const f4*)&vqd[o];
        const f4 w2 = (X + 4 < WW)   ? *(const f4*)&vqd[o + 4] : z4;
        const float s0 = ((w0.x + w0.y) + (w0.z + w0.w))
                       + ((w1.x + w1.y) + (w1.z + w1.w)) + w2.x;
        const float s1 = s0 + w2.y - w0.x;
        const float s2 = s1 + w2.z - w0.y;
        const float s3 = s2 + w2.w - w0.z;
        const float s[4] = {s0, s1, s2, s3};

        const f4 ls = *(const f4*)&LSum[o];
        const f4 sl = *(const f4*)&sqLa[o];

        if (X >= d && X + 3 < WW - d) {
            // interior fast path: all 4 outputs valid, no zero regions
            const int od = o - d;
            const f4 rn = (f4)(*(const f4u*)&RSn[od]);
            const f4 sr = (f4)(*(const f4u*)&sqRa[od]);
            f4 cl;
#pragma unroll
            for (int j = 0; j < 4; ++j) {
                const float num = fmaf(-ls[j], rn[j], s[j]) + 1e-6f;
                const float den = fmaf(sl[j], sr[j], 1e-6f);
                cl[j] = num * __builtin_amdgcn_rcpf(den);
            }
            *(f4u*)&outRp[od] = (f4u)cl;
            *(f4*)&outLp[o]   = cl;
        } else {
#pragma unroll
            for (int j = 0; j < 4; ++j) {
                const int x = X + j;
                float cl = 0.f;
                if (x >= d) {
                    const int od = o + j - d;
                    const float num = fmaf(-ls[j], RSn[od], s[j]) + 1e-6f;
                    const float den = fmaf(sl[j], sqRa[od], 1e-6f);
                    cl = num * __builtin_amdgcn_rcpf(den);
                    outRp[od] = cl;
                }
                outLp[o + j] = cl;
                if (x >= WW - d) outRp[o + j] = 0.f;
            }
        }
    }
}

// ---------------------------------------------------------------------------
extern "C" void kernel_launch(void* const* d_in, const int* in_sizes, int n_in,
                              void* d_out, int out_size, void* d_ws, size_t ws_size,
                              hipStream_t stream) {
    const float* L = (const float*)d_in[0];
    const float* R = (const float*)d_in[1];
    float* out = (float*)d_out;
    float* ws = (float*)d_ws;

    float* hsL  = ws + 0 * (size_t)NP;
    float* hsLL = ws + 1 * (size_t)NP;
    float* hsR  = ws + 2 * (size_t)NP;
    float* hsRR = ws + 3 * (size_t)NP;
    float* LSum = ws + 4 * (size_t)NP;
    float* sqLa = ws + 5 * (size_t)NP;
    float* RSn  = ws + 6 * (size_t)NP;
    float* sqRa = ws + 7 * (size_t)NP;
    float* vq   = ws + 8 * (size_t)NP;   // 60 * NP floats = 124.4 MB

    dim3 blk(256);
    dim3 g1((WW + 255) / 256, HH);
    k_stats_h<<<g1, blk, 0, stream>>>(L, R, hsL, hsLL, hsR, hsRR);
    k_stats_v<<<g1, blk, 0, stream>>>(hsL, hsLL, hsR, hsRR, LSum, sqLa, RSn, sqRa);

    dim3 g2(ND, HH / YS);                // (60 d fastest, 15 strips)
    k_vq<<<g2, blk, 0, stream>>>(L, R, vq);

    dim3 g3(ND, HH / RY);                // (60 d fastest, 135 ygroups)
    k_cost_h<<<g3, blk, 0, stream>>>(vq, LSum, sqLa, RSn, sqRa, out);
}